// Round 3
// baseline (3291.013 us; speedup 1.0000x reference)
//
#include <hip/hip_runtime.h>
#include <hip/hip_bf16.h>

typedef unsigned short u16;
typedef unsigned int   u32;

// ---------- helpers ----------
__device__ __forceinline__ float bf2f(u16 u) {
    union { u32 i; float f; } v; v.i = ((u32)u) << 16; return v.f;
}
__device__ __forceinline__ void unpack8(uint4 u, float* w) {
    w[0] = bf2f((u16)(u.x & 0xffff)); w[1] = bf2f((u16)(u.x >> 16));
    w[2] = bf2f((u16)(u.y & 0xffff)); w[3] = bf2f((u16)(u.y >> 16));
    w[4] = bf2f((u16)(u.z & 0xffff)); w[5] = bf2f((u16)(u.z >> 16));
    w[6] = bf2f((u16)(u.w & 0xffff)); w[7] = bf2f((u16)(u.w >> 16));
}
__device__ __forceinline__ float sigm(float x) { return 1.0f / (1.0f + expf(-x)); }
// flag-adaptive scalar load: f==1 -> f32, f==0 -> bf16
__device__ __forceinline__ float ldf(const void* p, size_t i, int f) {
    return f ? ((const float*)p)[i] : bf2f(((const u16*)p)[i]);
}

#define PAD_IDX 100000
#define KN 50

// ---------- dtype probe: even-index u16s of emb decode small iff data is bf16 ----------
__global__ __launch_bounds__(256)
void probe_dtype(const void* __restrict__ emb, int* __restrict__ flag) {
    __shared__ float smax[256];
    const int t = threadIdx.x;
    float v = fabsf(bf2f(((const u16*)emb)[2 * t]));
    if (!(v < 1.0f)) v = 1e9f;                 // NaN-safe: NaN counts as large
    smax[t] = v; __syncthreads();
    for (int off = 128; off > 0; off >>= 1) {
        if (t < off) smax[t] = fmaxf(smax[t], smax[t + off]);
        __syncthreads();
    }
    if (t == 0) flag[0] = (smax[0] < 1.0f) ? 0 : 1;   // 0=bf16, 1=f32
}

// ---------- workspace-too-small sentinel ----------
__global__ __launch_bounds__(256)
void signal_fail(float* out) {      // write as f32 AND bf16-compatible signature
    int i = blockIdx.x * 256 + threadIdx.x;
    if (i < 4096) out[i] = 12345.0f;   // bf16 view of high u16 = 0x4640 = 12288, also distinctive
}

// ---------- Part A: fused neighbor encoder, one block per (b, side) ----------
__global__ __launch_bounds__(256)
void neighbor_enc(const int* __restrict__ conn, const int* __restrict__ selfids,
                  int sstride, int soff,
                  const void* __restrict__ emb,
                  const void* __restrict__ projw,
                  const void* __restrict__ projlb, const void* __restrict__ projb,
                  const void* __restrict__ gatew, const void* __restrict__ gatelb,
                  const void* __restrict__ gateb,
                  const int* __restrict__ flag,
                  float* __restrict__ outX, int out_row_off, int out_col_off)
{
    __shared__ float nvt[256][52];   // [d][k], cols 50..51 zero pad
    __shared__ float sself[256];
    __shared__ int   sconn[100];
    __shared__ float sred[256];
    __shared__ float sgate;

    const int b = blockIdx.x;
    const int t = threadIdx.x;
    const int isf = flag[0];

    if (t < 100) sconn[t] = conn[b * 100 + t];
    const int sid = selfids[b * sstride + soff];
    sself[t] = ldf(emb, (size_t)sid * 256 + t, isf);
    __syncthreads();

    float cnt = 0.f;
#pragma unroll
    for (int k = 0; k < KN; k++) if (sconn[2 * k] != PAD_IDX) cnt += 1.f;

    for (int k = 0; k < KN; k++) {
        const int rel = sconn[2 * k], ent = sconn[2 * k + 1];
        float rv = ldf(emb, (size_t)rel * 256 + t, isf);
        float ev = ldf(emb, (size_t)ent * 256 + t, isf);
        nvt[t][k] = rv * ev;
    }
    nvt[t][50] = 0.f; nvt[t][51] = 0.f;
    __syncthreads();

    float acc[52];
#pragma unroll
    for (int i = 0; i < 52; i++) acc[i] = 0.f;

    for (int d0 = 0; d0 < 256; d0 += 8) {
        float wv[8];
        if (isf) {
            const float* wr = (const float*)projw + (size_t)t * 256 + d0;
#pragma unroll
            for (int q = 0; q < 8; q++) wv[q] = wr[q];
        } else {
            uint4 wl = *(const uint4*)((const u16*)projw + (size_t)t * 256 + d0);
            unpack8(wl, wv);
        }
#pragma unroll
        for (int jj = 0; jj < 8; jj++) {
            const float w = wv[jj];
            const float4* nvp = (const float4*)(&nvt[d0 + jj][0]);
#pragma unroll
            for (int q = 0; q < 13; q++) {
                float4 v = nvp[q];
                acc[4 * q + 0] = fmaf(v.x, w, acc[4 * q + 0]);
                acc[4 * q + 1] = fmaf(v.y, w, acc[4 * q + 1]);
                acc[4 * q + 2] = fmaf(v.z, w, acc[4 * q + 2]);
                acc[4 * q + 3] = fmaf(v.w, w, acc[4 * q + 3]);
            }
        }
    }

    const float pb = ldf(projlb, t, isf) + ldf(projb, t, isf);
    float s = 0.f;
#pragma unroll
    for (int k = 0; k < KN; k++) {
        float v = acc[k] + pb;
        v = v > 0.f ? v : 0.01f * v;          // leaky_relu(0.01)
        if (sconn[2 * k] != PAD_IDX) s += v;
    }
    const float agg = s / (cnt + 1e-9f);

    sred[t] = sself[t] * ldf(gatew, t, isf) + agg * ldf(gatew, 256 + t, isf);
    __syncthreads();
    for (int off = 128; off > 0; off >>= 1) {
        if (t < off) sred[t] += sred[t + off];
        __syncthreads();
    }
    if (t == 0) sgate = sigm(sred[0] + ldf(gatelb, 0, isf) + ldf(gateb, 0, isf));
    __syncthreads();

    outX[(size_t)(out_row_off + b) * 512 + out_col_off + t] = tanhf(sself[t] + sgate * agg);
}

// ---------- generic f32 GEMM: C = act(A @ W^T + bias0 + resid) ----------
#define GM 128
#define GN 128
#define GK 32
__global__ __launch_bounds__(256)
void gemm_f32_kernel(const float* __restrict__ A, int lda,
                     const void* __restrict__ W, int ldw,
                     float* __restrict__ C, int ldc,
                     int M, int N, int Kd,
                     const void* __restrict__ bias0,
                     const float* __restrict__ resid, int ldr,
                     int act, const int* __restrict__ flag)
{
    __shared__ float As[GK][GM + 4];
    __shared__ float Bs[GK][GN + 4];

    const int t = threadIdx.x;
    const int isf = flag[0];
    const int m0 = blockIdx.y * GM;
    const int n0 = blockIdx.x * GN;
    const int tx = t & 15, ty = t >> 4;
    const int srow = t & 127;
    const int sh = t >> 7;

    float acc[8][8];
#pragma unroll
    for (int i = 0; i < 8; i++)
#pragma unroll
        for (int j = 0; j < 8; j++) acc[i][j] = 0.f;

    for (int k0 = 0; k0 < Kd; k0 += GK) {
        {
            const int gm = m0 + srow;
            float va[16];
            if (gm < M) {
                const float4* ap = (const float4*)(A + (size_t)gm * lda + k0 + sh * 16);
#pragma unroll
                for (int q = 0; q < 4; q++) {
                    float4 v = ap[q];
                    va[q * 4 + 0] = v.x; va[q * 4 + 1] = v.y;
                    va[q * 4 + 2] = v.z; va[q * 4 + 3] = v.w;
                }
            } else {
#pragma unroll
                for (int i = 0; i < 16; i++) va[i] = 0.f;
            }
#pragma unroll
            for (int i = 0; i < 16; i++) As[sh * 16 + i][srow] = va[i];
        }
        {
            const int gn = n0 + srow;
            float vb[16];
            if (gn < N) {
                if (isf) {
                    const float* wr = (const float*)W + (size_t)gn * ldw + k0 + sh * 16;
#pragma unroll
                    for (int i = 0; i < 16; i++) vb[i] = wr[i];
                } else {
                    const uint4* wp = (const uint4*)((const u16*)W + (size_t)gn * ldw + k0 + sh * 16);
                    uint4 u0 = wp[0], u1 = wp[1];
                    unpack8(u0, vb); unpack8(u1, vb + 8);
                }
            } else {
#pragma unroll
                for (int i = 0; i < 16; i++) vb[i] = 0.f;
            }
#pragma unroll
            for (int i = 0; i < 16; i++) Bs[sh * 16 + i][srow] = vb[i];
        }
        __syncthreads();

#pragma unroll 4
        for (int kk = 0; kk < GK; kk++) {
            float a[8], bb[8];
            const float4* ap4 = (const float4*)(&As[kk][ty * 8]);
            float4 a0 = ap4[0], a1 = ap4[1];
            a[0] = a0.x; a[1] = a0.y; a[2] = a0.z; a[3] = a0.w;
            a[4] = a1.x; a[5] = a1.y; a[6] = a1.z; a[7] = a1.w;
            const float4* bp4 = (const float4*)(&Bs[kk][tx * 8]);
            float4 b0 = bp4[0], b1 = bp4[1];
            bb[0] = b0.x; bb[1] = b0.y; bb[2] = b0.z; bb[3] = b0.w;
            bb[4] = b1.x; bb[5] = b1.y; bb[6] = b1.z; bb[7] = b1.w;
#pragma unroll
            for (int i = 0; i < 8; i++)
#pragma unroll
                for (int j = 0; j < 8; j++) acc[i][j] = fmaf(a[i], bb[j], acc[i][j]);
        }
        __syncthreads();
    }

#pragma unroll
    for (int i = 0; i < 8; i++) {
        const int gm = m0 + ty * 8 + i;
        if (gm >= M) continue;
#pragma unroll
        for (int q = 0; q < 2; q++) {
            const int gn = n0 + tx * 8 + q * 4;
            float4 v;
            float* vp = (float*)&v;
#pragma unroll
            for (int j = 0; j < 4; j++) {
                float x = acc[i][q * 4 + j];
                const int nn = gn + j;
                if (bias0) x += ldf(bias0, nn, isf);
                if (resid) x += resid[(size_t)gm * ldr + nn];
                if (act == 1) x = x > 0.f ? x : 0.f;
                vp[j] = x;
            }
            *(float4*)(C + (size_t)gm * ldc + gn) = v;
        }
    }
}

// ---------- fused LSTM step: gates = [ENC|h] @ Wp^T + fb ; cell update in epilogue ----------
// Wpf (f32) is gate-interleaved: row n = 4*j + g  (g: 0=i,1=f,2=g,3=o)
__global__ __launch_bounds__(256)
void lstm_gemm(const float* __restrict__ ENCq,      // [4096,512]
               const float* __restrict__ hin,       // [4096,512] (unused if Keff==512)
               const float* __restrict__ Wpf,       // [4096,1024] f32
               const float* __restrict__ fb,        // [4096] f32 bias (perm order)
               float* __restrict__ cst,             // [4096,1024] f32 cell state
               float* __restrict__ hout,            // [4096,512]
               int step1, int Keff)
{
    __shared__ float As[GK][GM + 4];
    __shared__ float Bs[GK][GN + 4];

    const int t = threadIdx.x;
    const int m0 = blockIdx.y * GM;
    const int n0 = blockIdx.x * GN;
    const int tx = t & 15, ty = t >> 4;
    const int srow = t & 127;
    const int sh = t >> 7;

    float acc[8][8];
#pragma unroll
    for (int i = 0; i < 8; i++)
#pragma unroll
        for (int j = 0; j < 8; j++) acc[i][j] = 0.f;

    for (int k0 = 0; k0 < Keff; k0 += GK) {
        {
            const int gm = m0 + srow;
            const float* Abase = (k0 < 512) ? (ENCq + (size_t)gm * 512 + k0)
                                            : (hin  + (size_t)gm * 512 + (k0 - 512));
            const float4* ap = (const float4*)(Abase + sh * 16);
            float va[16];
#pragma unroll
            for (int q = 0; q < 4; q++) {
                float4 v = ap[q];
                va[q * 4 + 0] = v.x; va[q * 4 + 1] = v.y;
                va[q * 4 + 2] = v.z; va[q * 4 + 3] = v.w;
            }
#pragma unroll
            for (int i = 0; i < 16; i++) As[sh * 16 + i][srow] = va[i];
        }
        {
            const int gn = n0 + srow;
            const float* wr = Wpf + (size_t)gn * 1024 + k0 + sh * 16;
            float vb[16];
#pragma unroll
            for (int i = 0; i < 16; i++) vb[i] = wr[i];
#pragma unroll
            for (int i = 0; i < 16; i++) Bs[sh * 16 + i][srow] = vb[i];
        }
        __syncthreads();

#pragma unroll 4
        for (int kk = 0; kk < GK; kk++) {
            float a[8], bb[8];
            const float4* ap4 = (const float4*)(&As[kk][ty * 8]);
            float4 a0 = ap4[0], a1 = ap4[1];
            a[0] = a0.x; a[1] = a0.y; a[2] = a0.z; a[3] = a0.w;
            a[4] = a1.x; a[5] = a1.y; a[6] = a1.z; a[7] = a1.w;
            const float4* bp4 = (const float4*)(&Bs[kk][tx * 8]);
            float4 b0 = bp4[0], b1 = bp4[1];
            bb[0] = b0.x; bb[1] = b0.y; bb[2] = b0.z; bb[3] = b0.w;
            bb[4] = b1.x; bb[5] = b1.y; bb[6] = b1.z; bb[7] = b1.w;
#pragma unroll
            for (int i = 0; i < 8; i++)
#pragma unroll
                for (int j = 0; j < 8; j++) acc[i][j] = fmaf(a[i], bb[j], acc[i][j]);
        }
        __syncthreads();
    }

#pragma unroll
    for (int i = 0; i < 8; i++) {
        const int gm = m0 + ty * 8 + i;
#pragma unroll
        for (int jj = 0; jj < 2; jj++) {
            const int nb = n0 + tx * 8 + jj * 4;
            const int j = nb >> 2;                  // 0..1023
            const float gi = acc[i][jj * 4 + 0] + fb[nb + 0];
            const float gf = acc[i][jj * 4 + 1] + fb[nb + 1];
            const float gg = acc[i][jj * 4 + 2] + fb[nb + 2];
            const float go = acc[i][jj * 4 + 3] + fb[nb + 3];
            const float c0 = step1 ? 0.f : cst[(size_t)gm * 1024 + j];
            const float cn = sigm(gf) * c0 + sigm(gi) * tanhf(gg);
            cst[(size_t)gm * 1024 + j] = cn;
            if (j < 512)
                hout[(size_t)gm * 512 + j] = ENCq[(size_t)gm * 512 + j] + sigm(go) * tanhf(cn);
        }
    }
}

// ---------- row LayerNorm (512 cols, in place) ----------
__global__ __launch_bounds__(256)
void ln_kernel(float* __restrict__ X, const void* __restrict__ g, const void* __restrict__ b,
               const int* __restrict__ flag)
{
    const int r = blockIdx.x;
    const int t = threadIdx.x;
    const int isf = flag[0];
    float* row = X + (size_t)r * 512;
    float x0 = row[t], x1 = row[t + 256];

    __shared__ float sr[256];
    sr[t] = x0 + x1; __syncthreads();
    for (int off = 128; off > 0; off >>= 1) { if (t < off) sr[t] += sr[t + off]; __syncthreads(); }
    const float mu = sr[0] / 512.f;
    __syncthreads();
    float d0 = x0 - mu, d1 = x1 - mu;
    sr[t] = d0 * d0 + d1 * d1; __syncthreads();
    for (int off = 128; off > 0; off >>= 1) { if (t < off) sr[t] += sr[t + off]; __syncthreads(); }
    const float var = sr[0] / 512.f;
    const float inv = 1.0f / sqrtf(var + 1e-5f);
    row[t]       = ldf(g, t, isf) * d0 * inv + ldf(b, t, isf);
    row[t + 256] = ldf(g, 256 + t, isf) * d1 * inv + ldf(b, 256 + t, isf);
}

// ---------- Wp build (f32 out): Wpf[4j+g] = [w_ih row | w_hh row cols 0..511] ----------
__global__ __launch_bounds__(256)
void wp_build(const void* __restrict__ wih, const void* __restrict__ whh,
              const void* __restrict__ bih, const void* __restrict__ bhh,
              const int* __restrict__ flag,
              float* __restrict__ Wpf, float* __restrict__ fb0p)
{
    const int n = blockIdx.x;           // 0..4095 dest row
    const int t = threadIdx.x;
    const int isf = flag[0];
    const int j = n >> 2, g = n & 3;
    const int r = g * 1024 + j;         // source row
#pragma unroll
    for (int q = 0; q < 4; q++) {
        const int k = t * 4 + q;        // 0..1023
        Wpf[(size_t)n * 1024 + k] =
            (k < 512) ? ldf(wih, (size_t)r * 512 + k, isf)
                      : ldf(whh, (size_t)r * 1024 + (k - 512), isf);
    }
    if (t == 0) fb0p[n] = ldf(bih, r, isf) + ldf(bhh, r, isf);
}

// ---------- support_g + fb1p = fb0p + (sg @ w_hh[:,512:]^T) permuted ----------
__global__ __launch_bounds__(256)
void sg_cvec_kernel(const float* __restrict__ ENC, const void* __restrict__ whh,
                    const float* __restrict__ fb0p, const int* __restrict__ flag,
                    float* __restrict__ sg, float* __restrict__ fb1p)
{
    __shared__ float ssg[512];
    const int t = threadIdx.x;
    const int isf = flag[0];
#pragma unroll
    for (int rep = 0; rep < 2; rep++) {
        const int j = t + rep * 256;
        float v = 0.f;
#pragma unroll
        for (int i = 0; i < 5; i++) v += ENC[(size_t)(4096 + i) * 512 + j];
        v *= 0.2f;
        ssg[j] = v;
        if (blockIdx.x == 0) sg[j] = v;
    }
    __syncthreads();
    const int n = blockIdx.x * 256 + t;   // 0..4095 (perm order)
    const int r = (n & 3) * 1024 + (n >> 2);
    float a = 0.f;
    for (int j = 0; j < 512; j++)
        a = fmaf(ssg[j], ldf(whh, (size_t)r * 1024 + 512 + j, isf), a);
    fb1p[n] = fb0p[n] + a;
}

// ---------- final: out[b] = dot(h[b], support_g), dtype per flag ----------
__global__ __launch_bounds__(256)
void final_dot(const float* __restrict__ h, const float* __restrict__ sg,
               void* __restrict__ out, const int* __restrict__ flag)
{
    const int wid = threadIdx.x >> 6, lane = threadIdx.x & 63;
    const int b = blockIdx.x * 4 + wid;
    const float* hr = h + (size_t)b * 512;
    float s = 0.f;
#pragma unroll
    for (int q = 0; q < 8; q++) s = fmaf(hr[lane + q * 64], sg[lane + q * 64], s);
    for (int off = 32; off > 0; off >>= 1) s += __shfl_down(s, off);
    if (lane == 0) {
        if (!isfinite(s)) s = 7777.0f;          // triage signature: pipeline NaN
        if (flag[0]) ((float*)out)[b] = s;
        else ((__hip_bfloat16*)out)[b] = __float2bfloat16(s);
    }
}

// ---------- launcher ----------
extern "C" void kernel_launch(void* const* d_in, const int* in_sizes, int n_in,
                              void* d_out, int out_size, void* d_ws, size_t ws_size,
                              hipStream_t stream)
{
    (void)in_sizes; (void)n_in; (void)out_size;
    const int* query   = (const int*)d_in[0];
    const int* support = (const int*)d_in[1];
    const int* q_l1    = (const int*)d_in[2];
    const int* q_r1    = (const int*)d_in[3];
    const int* s_l1    = (const int*)d_in[4];
    const int* s_r1    = (const int*)d_in[5];
    const void* emb    = d_in[6];
    const void* projw  = d_in[7];
    const void* projlb = d_in[8];
    const void* projb  = d_in[9];
    const void* gatew  = d_in[10];
    const void* gatelb = d_in[11];
    const void* gateb  = d_in[12];
    const void* sew1   = d_in[13];
    const void* seb1   = d_in[14];
    const void* sew2   = d_in[15];
    const void* seb2   = d_in[16];
    const void* lng    = d_in[17];
    const void* lnb    = d_in[18];
    const void* wih    = d_in[19];
    const void* whh    = d_in[20];
    const void* bih    = d_in[21];
    const void* bhh    = d_in[22];

    // ---- workspace layout (float offsets), total 14,705,168 floats = 58.82 MB ----
    float* base = (float*)d_ws;
    int*   flag = (int*)base;                            // 16
    float* sg   = base + 16;                             // 512
    float* fb0p = base + 528;                            // 4096
    float* fb1p = base + 4624;                           // 4096
    float* Wpf  = base + 8720;                           // 4096*1024
    float* ENC  = base + 4203024;                        // [4104,512]
    float* Hb   = base + 6304272;                        // [4104,1024]; cst overlays (dead after GEMM2)
    float* cst  = Hb;                                    // [4096,1024]
    float* X    = base + 10506768;                       // [4104,512]; h0 overlays (dead after GEMM2)
    float* h0   = X;                                     // [4096,512]
    float* h1   = base + 12608016;                       // [4096,512]

    const size_t NEEDED = 14705168ull * 4ull;
    if (ws_size < NEEDED) {      // distinguishable failure signature: out = 12345.0
        signal_fail<<<16, 256, 0, stream>>>((float*)d_out);
        return;
    }

    // dtype probe first; all downstream kernels branch on flag (device-side)
    probe_dtype<<<1, 256, 0, stream>>>(emb, flag);

    // Part A: neighbor encoders -> X
    neighbor_enc<<<4096, 256, 0, stream>>>(q_l1, query, 2, 0, emb, projw, projlb, projb,
                                           gatew, gatelb, gateb, flag, X, 0, 0);
    neighbor_enc<<<4096, 256, 0, stream>>>(q_r1, query, 2, 1, emb, projw, projlb, projb,
                                           gatew, gatelb, gateb, flag, X, 0, 256);
    neighbor_enc<<<5, 256, 0, stream>>>(s_l1, support, 2, 0, emb, projw, projlb, projb,
                                        gatew, gatelb, gateb, flag, X, 4096, 0);
    neighbor_enc<<<5, 256, 0, stream>>>(s_r1, support, 2, 1, emb, projw, projlb, projb,
                                        gatew, gatelb, gateb, flag, X, 4096, 256);

    // Wpf / fb0p build
    wp_build<<<4096, 256, 0, stream>>>(wih, whh, bih, bhh, flag, Wpf, fb0p);

    // Part B: support encoder over 4101 rows
    gemm_f32_kernel<<<dim3(8, 33), 256, 0, stream>>>(
        X, 512, sew1, 512, Hb, 1024, 4101, 1024, 512,
        seb1, nullptr, 0, 1, flag);
    gemm_f32_kernel<<<dim3(4, 33), 256, 0, stream>>>(
        Hb, 1024, sew2, 1024, ENC, 512, 4101, 512, 1024,
        seb2, X, 512, 0, flag);
    ln_kernel<<<4101, 256, 0, stream>>>(ENC, lng, lnb, flag);

    // support_g + permuted step-2+ bias
    sg_cvec_kernel<<<16, 256, 0, stream>>>(ENC, whh, fb0p, flag, sg, fb1p);

    // LSTM steps (cell fused into GEMM epilogue); h0 overlays X (X dead after GEMM2)
    lstm_gemm<<<dim3(32, 32), 256, 0, stream>>>(ENC, h0, Wpf, fb0p, cst, h0, 1, 512);
    lstm_gemm<<<dim3(32, 32), 256, 0, stream>>>(ENC, h0, Wpf, fb1p, cst, h1, 0, 1024);
    lstm_gemm<<<dim3(32, 32), 256, 0, stream>>>(ENC, h1, Wpf, fb1p, cst, h0, 0, 1024);
    lstm_gemm<<<dim3(32, 32), 256, 0, stream>>>(ENC, h0, Wpf, fb1p, cst, h1, 0, 1024);

    // final scores
    final_dot<<<1024, 256, 0, stream>>>(h1, sg, d_out, flag);
}

// Round 7
// 1194.494 us; speedup vs baseline: 2.7552x; 2.7552x over previous
//
#include <hip/hip_runtime.h>
#include <hip/hip_bf16.h>

typedef unsigned short u16;
typedef unsigned int   u32;
typedef __attribute__((ext_vector_type(8))) short bf16x8;   // 8 bf16 = 4 VGPRs
typedef __attribute__((ext_vector_type(4))) float f32x4;

// ---------- helpers ----------
__device__ __forceinline__ float bf2f(u16 u) {
    union { u32 i; float f; } v; v.i = ((u32)u) << 16; return v.f;
}
__device__ __forceinline__ u16 f2bf(float f) {
    __hip_bfloat16 h = __float2bfloat16(f);
    return *reinterpret_cast<u16*>(&h);
}
__device__ __forceinline__ float sigm(float x) { return 1.0f / (1.0f + expf(-x)); }

#define PAD_IDX 100000

// ---------- diagnostics ----------
__global__ __launch_bounds__(64)
void zero_flags(int* f) {
    if (threadIdx.x < 16) f[threadIdx.x] = (threadIdx.x < 8) ? 0 : 0x7FFFFFFF;
}
__global__ __launch_bounds__(256)
void scan_bf16(const u16* __restrict__ p, long n, int bit, int* __restrict__ flag) {
    long i = (long)blockIdx.x * 256 + threadIdx.x;
    const long stride = (long)gridDim.x * 256;
    long bad = -1;
    for (; i < n; i += stride) {
        if ((p[i] & 0x7F80u) == 0x7F80u) { bad = i; break; }
    }
    if (bad >= 0) { atomicOr(flag + bit, 1); atomicMin(&flag[8 + bit], (int)(bad >> 18)); }
}
__global__ __launch_bounds__(256)
void scan_f32(const float* __restrict__ p, long n, int bit, int* __restrict__ flag) {
    long i = (long)blockIdx.x * 256 + threadIdx.x;
    const long stride = (long)gridDim.x * 256;
    long bad = -1;
    for (; i < n; i += stride) {
        if ((((const u32*)p)[i] & 0x7F800000u) == 0x7F800000u) { bad = i; break; }
    }
    if (bad >= 0) { atomicOr(flag + bit, 1); atomicMin(&flag[8 + bit], (int)(bad >> 18)); }
}

// ---------- workspace-too-small sentinel ----------
__global__ __launch_bounds__(256)
void signal_fail(float* out) {
    int i = blockIdx.x * 256 + threadIdx.x;
    if (i < 4096) out[i] = 12345.0f;
}

// ---------- f32 -> bf16 conversion ----------
__global__ __launch_bounds__(256)
void conv_bf16(const float* __restrict__ in, u16* __restrict__ out, long n) {
    long i = ((long)blockIdx.x * 256 + threadIdx.x) * 4;
    const long stride = (long)gridDim.x * 256 * 4;
    for (; i < n; i += stride) {
        float4 v = *(const float4*)(in + i);
        u16 o[4] = { f2bf(v.x), f2bf(v.y), f2bf(v.z), f2bf(v.w) };
        *(uint2*)(out + i) = *(uint2*)o;
    }
}

// ---------- Part A: neighbor encoder, MFMA projection; one block per (b,side) ----------
// emb is f32 (L3-resident). nv computed f32, rounded to bf16 A-fragments.
__global__ __launch_bounds__(256)
void neighbor_mfma(const int* __restrict__ conn, const int* __restrict__ selfids,
                   int sstride, int soff,
                   const float* __restrict__ emb, const u16* __restrict__ projw_b,
                   const float* __restrict__ projlb, const float* __restrict__ projb,
                   const float* __restrict__ gatew, const float* __restrict__ gatelb,
                   const float* __restrict__ gateb,
                   u16* __restrict__ outX, int row_off, int col_off)
{
    __shared__ u16   nvA[64][264];     // [k-row][d], pad 256->264 (2-way conflicts only)
    __shared__ int   sconn[100];
    __shared__ float maskv[64];
    __shared__ float sagg[256];
    __shared__ float sred[256];
    __shared__ float sgate;

    const int b = blockIdx.x, t = threadIdx.x;
    const int w = t >> 6, lane = t & 63, quad = lane >> 4, cc = lane & 15;

    if (t < 100) sconn[t] = conn[b * 100 + t];
    const int sid = selfids[b * sstride + soff];
    const float selfv = emb[(size_t)sid * 256 + t];
    __syncthreads();

    float cnt = 0.f;
    for (int k = 0; k < 50; k++) if (sconn[2 * k] != PAD_IDX) cnt += 1.f;
    if (t < 64) maskv[t] = (t < 50 && sconn[2 * t] != PAD_IDX) ? 1.f : 0.f;

    for (int k = 0; k < 50; k++) {
        const int rel = sconn[2 * k], ent = sconn[2 * k + 1];
        nvA[k][t] = f2bf(emb[(size_t)rel * 256 + t] * emb[(size_t)ent * 256 + t]);
    }
    for (int k = 50; k < 64; k++) nvA[k][t] = 0;
    __syncthreads();

    f32x4 acc[4][4];
#pragma unroll
    for (int mt = 0; mt < 4; mt++)
#pragma unroll
        for (int nt = 0; nt < 4; nt++) acc[mt][nt] = (f32x4){0.f, 0.f, 0.f, 0.f};

    for (int k0 = 0; k0 < 256; k0 += 32) {
        bf16x8 a[4];
#pragma unroll
        for (int mt = 0; mt < 4; mt++)
            a[mt] = *(const bf16x8*)&nvA[mt * 16 + cc][k0 + quad * 8];
#pragma unroll
        for (int nt = 0; nt < 4; nt++) {
            const int e = (w * 4 + nt) * 16 + cc;
            bf16x8 bv = *(const bf16x8*)(projw_b + (size_t)e * 256 + k0 + quad * 8);
#pragma unroll
            for (int mt = 0; mt < 4; mt++)
                acc[mt][nt] = __builtin_amdgcn_mfma_f32_16x16x32_bf16(a[mt], bv, acc[mt][nt], 0, 0, 0);
        }
    }

    float pbv[4], cs[4] = {0.f, 0.f, 0.f, 0.f};
#pragma unroll
    for (int nt = 0; nt < 4; nt++) {
        const int e = (w * 4 + nt) * 16 + cc;
        pbv[nt] = projlb[e] + projb[e];
    }
#pragma unroll
    for (int mt = 0; mt < 4; mt++)
#pragma unroll
        for (int r = 0; r < 4; r++) {
            const float mk = maskv[mt * 16 + quad * 4 + r];
#pragma unroll
            for (int nt = 0; nt < 4; nt++) {
                float v = acc[mt][nt][r] + pbv[nt];
                v = v > 0.f ? v : 0.01f * v;     // leaky_relu(0.01)
                cs[nt] += mk * v;
            }
        }
#pragma unroll
    for (int nt = 0; nt < 4; nt++) {
        cs[nt] += __shfl_xor(cs[nt], 16);
        cs[nt] += __shfl_xor(cs[nt], 32);
    }
    if (quad == 0) {
#pragma unroll
        for (int nt = 0; nt < 4; nt++) sagg[(w * 4 + nt) * 16 + cc] = cs[nt];
    }
    __syncthreads();

    const float agg = sagg[t] / (cnt + 1e-9f);
    sred[t] = selfv * gatew[t] + agg * gatew[256 + t];
    __syncthreads();
    for (int off = 128; off > 0; off >>= 1) {
        if (t < off) sred[t] += sred[t + off];
        __syncthreads();
    }
    if (t == 0) sgate = sigm(sred[0] + gatelb[0] + gateb[0]);
    __syncthreads();

    outX[(size_t)(row_off + b) * 512 + col_off + t] = f2bf(tanhf(selfv + sgate * agg));
}

// ---------- generic bf16 MFMA GEMM: C = act(A @ B^T + bias_f32 + resid_bf16) ----------
__global__ __launch_bounds__(256)
void gemm_bf16(const u16* __restrict__ A, int lda, const u16* __restrict__ B, int ldb,
               u16* __restrict__ C, int ldc, int M, int N, int K,
               const float* __restrict__ bias, const u16* __restrict__ resid, int ldr, int act)
{
    __shared__ u16 As[128][40];
    __shared__ u16 Bs[128][40];

    const int t = threadIdx.x;
    const int m0 = blockIdx.y * 128, n0 = blockIdx.x * 128;
    const int w = t >> 6, lane = t & 63, quad = lane >> 4, cc = lane & 15;
    const int wm = w >> 1, wn = w & 1;

    f32x4 acc[4][4];
#pragma unroll
    for (int mt = 0; mt < 4; mt++)
#pragma unroll
        for (int nt = 0; nt < 4; nt++) acc[mt][nt] = (f32x4){0.f, 0.f, 0.f, 0.f};

    for (int k0 = 0; k0 < K; k0 += 32) {
#pragma unroll
        for (int i = 0; i < 2; i++) {
            const int idx = t + i * 256;
            const int row = idx >> 2, seg = idx & 3;
            const int gm = m0 + row, gn = n0 + row;
            uint4 va = make_uint4(0, 0, 0, 0), vb = make_uint4(0, 0, 0, 0);
            if (gm < M) va = *(const uint4*)(A + (size_t)gm * lda + k0 + seg * 8);
            if (gn < N) vb = *(const uint4*)(B + (size_t)gn * ldb + k0 + seg * 8);
            *(uint4*)&As[row][seg * 8] = va;
            *(uint4*)&Bs[row][seg * 8] = vb;
        }
        __syncthreads();

        bf16x8 af[4], bfr[4];
#pragma unroll
        for (int mt = 0; mt < 4; mt++)
            af[mt] = *(const bf16x8*)&As[wm * 64 + mt * 16 + cc][quad * 8];
#pragma unroll
        for (int nt = 0; nt < 4; nt++)
            bfr[nt] = *(const bf16x8*)&Bs[wn * 64 + nt * 16 + cc][quad * 8];
#pragma unroll
        for (int mt = 0; mt < 4; mt++)
#pragma unroll
            for (int nt = 0; nt < 4; nt++)
                acc[mt][nt] = __builtin_amdgcn_mfma_f32_16x16x32_bf16(af[mt], bfr[nt], acc[mt][nt], 0, 0, 0);
        __syncthreads();
    }

#pragma unroll
    for (int mt = 0; mt < 4; mt++)
#pragma unroll
        for (int r = 0; r < 4; r++) {
            const int gm = m0 + wm * 64 + mt * 16 + quad * 4 + r;
            if (gm >= M) continue;
#pragma unroll
            for (int nt = 0; nt < 4; nt++) {
                const int gn = n0 + wn * 64 + nt * 16 + cc;
                if (gn >= N) continue;
                float x = acc[mt][nt][r];
                if (bias)  x += bias[gn];
                if (resid) x += bf2f(resid[(size_t)gm * ldr + gn]);
                if (act == 1) x = x > 0.f ? x : 0.f;
                C[(size_t)gm * ldc + gn] = f2bf(x);
            }
        }
}

// ---------- LSTM step: gates = [ENC|h] @ Wp^T + fb, fused cell epilogue ----------
__global__ __launch_bounds__(256)
void lstm_mfma(const u16* __restrict__ ENCb, const u16* __restrict__ hin,
               const u16* __restrict__ Wp, const float* __restrict__ fb,
               float* __restrict__ cst, u16* __restrict__ houtb, float* __restrict__ houtf,
               int step1, int Keff)
{
    __shared__ u16 As[128][40];
    __shared__ u16 Bs[128][40];

    const int t = threadIdx.x;
    const int m0 = blockIdx.y * 128, n0 = blockIdx.x * 128;
    const int w = t >> 6, lane = t & 63, quad = lane >> 4, cc = lane & 15;
    const int wm = w >> 1, wn = w & 1;

    f32x4 acc[4][4];
#pragma unroll
    for (int mt = 0; mt < 4; mt++)
#pragma unroll
        for (int nt = 0; nt < 4; nt++) acc[mt][nt] = (f32x4){0.f, 0.f, 0.f, 0.f};

    for (int k0 = 0; k0 < Keff; k0 += 32) {
        const u16* Aptr = (k0 < 512) ? ENCb : hin;
        const int kk = (k0 < 512) ? k0 : (k0 - 512);
#pragma unroll
        for (int i = 0; i < 2; i++) {
            const int idx = t + i * 256;
            const int row = idx >> 2, seg = idx & 3;
            uint4 va = *(const uint4*)(Aptr + (size_t)(m0 + row) * 512 + kk + seg * 8);
            uint4 vb = *(const uint4*)(Wp + (size_t)(n0 + row) * 1024 + k0 + seg * 8);
            *(uint4*)&As[row][seg * 8] = va;
            *(uint4*)&Bs[row][seg * 8] = vb;
        }
        __syncthreads();

        bf16x8 af[4], bfr[4];
#pragma unroll
        for (int mt = 0; mt < 4; mt++)
            af[mt] = *(const bf16x8*)&As[wm * 64 + mt * 16 + cc][quad * 8];
#pragma unroll
        for (int nt = 0; nt < 4; nt++)
            bfr[nt] = *(const bf16x8*)&Bs[wn * 64 + nt * 16 + cc][quad * 8];
#pragma unroll
        for (int mt = 0; mt < 4; mt++)
#pragma unroll
            for (int nt = 0; nt < 4; nt++)
                acc[mt][nt] = __builtin_amdgcn_mfma_f32_16x16x32_bf16(af[mt], bfr[nt], acc[mt][nt], 0, 0, 0);
        __syncthreads();
    }

#pragma unroll
    for (int mt = 0; mt < 4; mt++)
#pragma unroll
        for (int nt = 0; nt < 4; nt++) {
            const int nbase = n0 + wn * 64 + nt * 16 + (cc & ~3);
            const float fb0 = fb[nbase + 0], fb1 = fb[nbase + 1];
            const float fb2 = fb[nbase + 2], fb3 = fb[nbase + 3];
#pragma unroll
            for (int r = 0; r < 4; r++) {
                const float own = acc[mt][nt][r];
                const int src = lane & ~3;
                const float g0 = __shfl(own, src + 0);
                const float g1 = __shfl(own, src + 1);
                const float g2 = __shfl(own, src + 2);
                const float g3 = __shfl(own, src + 3);
                if ((cc & 3) == 0) {
                    const int gm = m0 + wm * 64 + mt * 16 + quad * 4 + r;
                    const int j = nbase >> 2;
                    const float gi = g0 + fb0, gf = g1 + fb1, gg = g2 + fb2, go = g3 + fb3;
                    const float c0 = step1 ? 0.f : cst[(size_t)gm * 1024 + j];
                    const float cn = sigm(gf) * c0 + sigm(gi) * tanhf(gg);
                    cst[(size_t)gm * 1024 + j] = cn;
                    if (j < 512) {
                        const float hv = bf2f(ENCb[(size_t)gm * 512 + j]) + sigm(go) * tanhf(cn);
                        houtb[(size_t)gm * 512 + j] = f2bf(hv);
                        houtf[(size_t)gm * 512 + j] = hv;
                    }
                }
            }
        }
}

// ---------- row LayerNorm (bf16 in place, f32 stats; f32 copy of support rows) ----------
__global__ __launch_bounds__(256)
void ln_kernel(u16* __restrict__ X, const float* __restrict__ g, const float* __restrict__ b,
               float* __restrict__ supf)
{
    const int r = blockIdx.x, t = threadIdx.x;
    u16* row = X + (size_t)r * 512;
    const float x0 = bf2f(row[t]), x1 = bf2f(row[t + 256]);

    __shared__ float sr[256];
    sr[t] = x0 + x1; __syncthreads();
    for (int off = 128; off > 0; off >>= 1) { if (t < off) sr[t] += sr[t + off]; __syncthreads(); }
    const float mu = sr[0] / 512.f;
    __syncthreads();
    const float d0 = x0 - mu, d1 = x1 - mu;
    sr[t] = d0 * d0 + d1 * d1; __syncthreads();
    for (int off = 128; off > 0; off >>= 1) { if (t < off) sr[t] += sr[t + off]; __syncthreads(); }
    const float inv = 1.0f / sqrtf(sr[0] / 512.f + 1e-5f);
    const float y0 = g[t] * d0 * inv + b[t];
    const float y1 = g[t + 256] * d1 * inv + b[t + 256];
    row[t]       = f2bf(y0);
    row[t + 256] = f2bf(y1);
    if (r >= 4096) {           // keep f32 copies of the 5 support rows for sg
        supf[(size_t)(r - 4096) * 512 + t]       = y0;
        supf[(size_t)(r - 4096) * 512 + t + 256] = y1;
    }
}

// ---------- Wp build from f32: Wp[4j+g] = bf16([w_ih row | w_hh row 0..511]) ----------
__global__ __launch_bounds__(256)
void wp_build(const float* __restrict__ wih, const float* __restrict__ whh,
              const float* __restrict__ bih, const float* __restrict__ bhh,
              u16* __restrict__ Wp, float* __restrict__ fb0p)
{
    const int n = blockIdx.x, t = threadIdx.x;
    const int j = n >> 2, g = n & 3, r = g * 1024 + j;
    const int k = t * 4;
    float4 v;
    if (k < 512) v = *(const float4*)(wih + (size_t)r * 512 + k);
    else         v = *(const float4*)(whh + (size_t)r * 1024 + (k - 512));
    u16 o[4] = { f2bf(v.x), f2bf(v.y), f2bf(v.z), f2bf(v.w) };
    *(uint2*)(Wp + (size_t)n * 1024 + k) = *(uint2*)o;
    if (t == 0) fb0p[n] = bih[r] + bhh[r];
}

// ---------- support_g (f32) + fb1p = fb0p + sg @ w_hh[:,512:]^T (perm order) ----------
__global__ __launch_bounds__(256)
void sg_cvec(const float* __restrict__ supf, const float* __restrict__ whh,
             const float* __restrict__ fb0p, float* __restrict__ sg, float* __restrict__ fb1p)
{
    __shared__ float ssg[512];
    const int t = threadIdx.x;
#pragma unroll
    for (int rep = 0; rep < 2; rep++) {
        const int jj = t + rep * 256;
        float v = 0.f;
#pragma unroll
        for (int i = 0; i < 5; i++) v += supf[(size_t)i * 512 + jj];
        v *= 0.2f;
        ssg[jj] = v;
        if (blockIdx.x == 0) sg[jj] = v;
    }
    __syncthreads();
    const int n = blockIdx.x * 256 + t;
    const int r = (n & 3) * 1024 + (n >> 2);
    float a = 0.f;
    for (int j = 0; j < 512; j++)
        a = fmaf(ssg[j], whh[(size_t)r * 1024 + 512 + j], a);
    fb1p[n] = fb0p[n] + a;
}

// ---------- final: out[b] = dot(hf[b], sg) -> f32 (R3-proven output dtype) ----------
__global__ __launch_bounds__(256)
void final_dot(const float* __restrict__ hf, const float* __restrict__ sg,
               float* __restrict__ out, const int* __restrict__ flag)
{
    const int wid = threadIdx.x >> 6, lane = threadIdx.x & 63;
    const int b = blockIdx.x * 4 + wid;
    const float* hr = hf + (size_t)b * 512;
    float s = 0.f;
#pragma unroll
    for (int q = 0; q < 8; q++) s = fmaf(hr[lane + q * 64], sg[lane + q * 64], s);
    for (int off = 32; off > 0; off >>= 1) s += __shfl_down(s, off);
    if (lane == 0) {
        float sig = 0.f;
#pragma unroll
        for (int bit = 0; bit < 8; bit++)
            if (sig == 0.f && flag[bit]) {
                int loc = flag[8 + bit];
                if (loc < 0 || loc > 9) loc = 9;
                sig = 1000.f * (bit + 1) + 100.f * loc;
            }
        if (sig != 0.f) s = sig;
        else if (!isfinite(s)) s = 7777.0f;
        out[b] = s;
    }
}

// ---------- launcher ----------
extern "C" void kernel_launch(void* const* d_in, const int* in_sizes, int n_in,
                              void* d_out, int out_size, void* d_ws, size_t ws_size,
                              hipStream_t stream)
{
    (void)in_sizes; (void)n_in; (void)out_size;
    const int* query     = (const int*)d_in[0];
    const int* support   = (const int*)d_in[1];
    const int* q_l1      = (const int*)d_in[2];
    const int* q_r1      = (const int*)d_in[3];
    const int* s_l1      = (const int*)d_in[4];
    const int* s_r1      = (const int*)d_in[5];
    const float* emb     = (const float*)d_in[6];
    const float* projw   = (const float*)d_in[7];
    const float* projlb  = (const float*)d_in[8];
    const float* projb   = (const float*)d_in[9];
    const float* gatew   = (const float*)d_in[10];
    const float* gatelb  = (const float*)d_in[11];
    const float* gateb   = (const float*)d_in[12];
    const float* sew1    = (const float*)d_in[13];
    const float* seb1    = (const float*)d_in[14];
    const float* sew2    = (const float*)d_in[15];
    const float* seb2    = (const float*)d_in[16];
    const float* lng     = (const float*)d_in[17];
    const float* lnb     = (const float*)d_in[18];
    const float* wih     = (const float*)d_in[19];
    const float* whh     = (const float*)d_in[20];
    const float* bih     = (const float*)d_in[21];
    const float* bhh     = (const float*)d_in[22];

    // ---- workspace layout (float offsets), total 13,155,344 floats = 52.6 MB ----
    float* base   = (float*)d_ws;
    float* sg     = base;                        // 512
    float* fb0p   = base + 512;                  // 4096
    float* fb1p   = base + 4608;                 // 4096
    float* supf   = base + 8704;                 // 5*512 f32
    u16*   projwb = (u16*)(base + 11264);        // 256*256 bf16 = 32768 f
    u16*   sew1b  = (u16*)(base + 44032);        // 1024*512 bf16 = 262144 f
    u16*   sew2b  = (u16*)(base + 306176);       // 512*1024 bf16 = 262144 f
    u16*   Wp     = (u16*)(base + 568320);       // 4096*1024 bf16 = 2097152 f
    u16*   X      = (u16*)(base + 2665472);      // [4104,512]  bf16 = 1050624 f
    u16*   ENCb   = (u16*)(base + 3716096);      // [4104,512]  bf16 = 1050624 f
    u16*   hb0    = (u16*)(base + 4766720);      // [4096,512]  bf16 = 1048576 f
    u16*   hb1    = (u16*)(base + 5815296);      // [4096,512]  bf16 = 1048576 f
    float* hf     = base + 6863872;              // [4096,512]  f32  = 2097152 f
    u16*   Hb     = (u16*)(base + 8961024);      // [4104,1024] bf16 (dead after GEMM2)
    float* cst    = base + 8961024;              // [4096,1024] f32 overlays Hb region
    int*   flg    = (int*)(base + 13155328);     // 16 ints

    const size_t NEEDED = 13155344ull * 4ull;
    if (ws_size < NEEDED) {
        signal_fail<<<16, 256, 0, stream>>>((float*)d_out);
        return;
    }

    zero_flags<<<1, 64, 0, stream>>>(flg);

    // weight conversions (f32 -> bf16 scratch)
    conv_bf16<<<64, 256, 0, stream>>>(projw, projwb, 65536);
    conv_bf16<<<512, 256, 0, stream>>>(sew1, sew1b, 524288);
    conv_bf16<<<512, 256, 0, stream>>>(sew2, sew2b, 524288);
    wp_build<<<4096, 256, 0, stream>>>(wih, whh, bih, bhh, Wp, fb0p);
    scan_bf16<<<512, 256, 0, stream>>>(Wp, 4096l * 1024, 4, flg);         // bit4 -> 5000

    // Part A: neighbor encoders -> X (bf16), emb read as f32 (L3-resident)
    neighbor_mfma<<<4096, 256, 0, stream>>>(q_l1, query, 2, 0, emb, projwb, projlb, projb,
                                            gatew, gatelb, gateb, X, 0, 0);
    neighbor_mfma<<<4096, 256, 0, stream>>>(q_r1, query, 2, 1, emb, projwb, projlb, projb,
                                            gatew, gatelb, gateb, X, 0, 256);
    neighbor_mfma<<<5, 256, 0, stream>>>(s_l1, support, 2, 0, emb, projwb, projlb, projb,
                                         gatew, gatelb, gateb, X, 4096, 0);
    neighbor_mfma<<<5, 256, 0, stream>>>(s_r1, support, 2, 1, emb, projwb, projlb, projb,
                                         gatew, gatelb, gateb, X, 4096, 256);
    scan_bf16<<<512, 256, 0, stream>>>(X, 4101l * 512, 0, flg);           // bit0 -> 1000

    // Part B: support encoder (MFMA)
    gemm_bf16<<<dim3(8, 33), 256, 0, stream>>>(
        X, 512, sew1b, 512, Hb, 1024, 4101, 1024, 512, seb1, nullptr, 0, 1);
    scan_bf16<<<512, 256, 0, stream>>>(Hb, 4101l * 1024, 1, flg);         // bit1 -> 2000
    gemm_bf16<<<dim3(4, 33), 256, 0, stream>>>(
        Hb, 1024, sew2b, 1024, ENCb, 512, 4101, 512, 1024, seb2, X, 512, 0);
    ln_kernel<<<4101, 256, 0, stream>>>(ENCb, lng, lnb, supf);
    scan_bf16<<<512, 256, 0, stream>>>(ENCb, 4101l * 512, 2, flg);        // bit2 -> 3000

    sg_cvec<<<16, 256, 0, stream>>>(supf, whh, fb0p, sg, fb1p);
    scan_f32<<<32, 256, 0, stream>>>(base, 11264, 3, flg);                // bit3 -> 4000

    // LSTM (cell fused into MFMA epilogue); cst overlays dead Hb
    lstm_mfma<<<dim3(32, 32), 256, 0, stream>>>(ENCb, hb0, Wp, fb0p, cst, hb0, hf, 1, 512);
    scan_f32<<<512, 256, 0, stream>>>(cst, 4096l * 1024, 5, flg);         // bit5 -> 6000
    scan_bf16<<<512, 256, 0, stream>>>(hb0, 4096l * 512, 6, flg);         // bit6 -> 7000
    lstm_mfma<<<dim3(32, 32), 256, 0, stream>>>(ENCb, hb0, Wp, fb1p, cst, hb1, hf, 0, 1024);
    scan_bf16<<<512, 256, 0, stream>>>(hb1, 4096l * 512, 7, flg);         // bit7 -> 8000
    lstm_mfma<<<dim3(32, 32), 256, 0, stream>>>(ENCb, hb1, Wp, fb1p, cst, hb0, hf, 0, 1024);
    lstm_mfma<<<dim3(32, 32), 256, 0, stream>>>(ENCb, hb0, Wp, fb1p, cst, hb1, hf, 0, 1024);

    // final scores (f32 out)
    final_dot<<<1024, 256, 0, stream>>>(hf, sg, (float*)d_out, flg);
}

// Round 8
// 807.838 us; speedup vs baseline: 4.0739x; 1.4786x over previous
//
#include <hip/hip_runtime.h>
#include <hip/hip_bf16.h>

typedef unsigned short u16;
typedef unsigned int   u32;
typedef __attribute__((ext_vector_type(8))) short bf16x8;   // 8 bf16 = 4 VGPRs
typedef __attribute__((ext_vector_type(4))) float f32x4;

// ---------- helpers ----------
__device__ __forceinline__ float bf2f(u16 u) {
    union { u32 i; float f; } v; v.i = ((u32)u) << 16; return v.f;
}
__device__ __forceinline__ u16 f2bf(float f) {
    __hip_bfloat16 h = __float2bfloat16(f);
    return *reinterpret_cast<u16*>(&h);
}
__device__ __forceinline__ float sigm(float x) { return 1.0f / (1.0f + expf(-x)); }

#define PAD_IDX 100000

// ---------- workspace-too-small sentinel ----------
__global__ __launch_bounds__(256)
void signal_fail(float* out) {
    int i = blockIdx.x * 256 + threadIdx.x;
    if (i < 4096) out[i] = 12345.0f;
}

// ---------- f32 -> bf16 conversion ----------
__global__ __launch_bounds__(256)
void conv_bf16(const float* __restrict__ in, u16* __restrict__ out, long n) {
    long i = ((long)blockIdx.x * 256 + threadIdx.x) * 4;
    const long stride = (long)gridDim.x * 256 * 4;
    for (; i < n; i += stride) {
        float4 v = *(const float4*)(in + i);
        u16 o[4] = { f2bf(v.x), f2bf(v.y), f2bf(v.z), f2bf(v.w) };
        *(uint2*)(out + i) = *(uint2*)o;
    }
}

// ---------- Part A: neighbor encoder, MFMA projection; one block per (b,side) ----------
__global__ __launch_bounds__(256)
void neighbor_mfma(const int* __restrict__ conn, const int* __restrict__ selfids,
                   int sstride, int soff,
                   const float* __restrict__ emb, const u16* __restrict__ projw_b,
                   const float* __restrict__ projlb, const float* __restrict__ projb,
                   const float* __restrict__ gatew, const float* __restrict__ gatelb,
                   const float* __restrict__ gateb,
                   u16* __restrict__ outX, int row_off, int col_off)
{
    __shared__ u16   nvA[64][264];     // [k-row][d], pad 256->264 (2-way conflicts only)
    __shared__ int   sconn[100];
    __shared__ float maskv[64];
    __shared__ float sagg[256];
    __shared__ float sred[256];
    __shared__ float sgate;

    const int b = blockIdx.x, t = threadIdx.x;
    const int w = t >> 6, lane = t & 63, quad = lane >> 4, cc = lane & 15;

    if (t < 100) sconn[t] = conn[b * 100 + t];
    const int sid = selfids[b * sstride + soff];
    const float selfv = emb[(size_t)sid * 256 + t];
    __syncthreads();

    float cnt = 0.f;
    for (int k = 0; k < 50; k++) if (sconn[2 * k] != PAD_IDX) cnt += 1.f;
    if (t < 64) maskv[t] = (t < 50 && sconn[2 * t] != PAD_IDX) ? 1.f : 0.f;

    for (int k = 0; k < 50; k++) {
        const int rel = sconn[2 * k], ent = sconn[2 * k + 1];
        nvA[k][t] = f2bf(emb[(size_t)rel * 256 + t] * emb[(size_t)ent * 256 + t]);
    }
    for (int k = 50; k < 64; k++) nvA[k][t] = 0;
    __syncthreads();

    f32x4 acc[4][4];
#pragma unroll
    for (int mt = 0; mt < 4; mt++)
#pragma unroll
        for (int nt = 0; nt < 4; nt++) acc[mt][nt] = (f32x4){0.f, 0.f, 0.f, 0.f};

    for (int k0 = 0; k0 < 256; k0 += 32) {
        bf16x8 a[4];
#pragma unroll
        for (int mt = 0; mt < 4; mt++)
            a[mt] = *(const bf16x8*)&nvA[mt * 16 + cc][k0 + quad * 8];
#pragma unroll
        for (int nt = 0; nt < 4; nt++) {
            const int e = (w * 4 + nt) * 16 + cc;
            bf16x8 bv = *(const bf16x8*)(projw_b + (size_t)e * 256 + k0 + quad * 8);
#pragma unroll
            for (int mt = 0; mt < 4; mt++)
                acc[mt][nt] = __builtin_amdgcn_mfma_f32_16x16x32_bf16(a[mt], bv, acc[mt][nt], 0, 0, 0);
        }
    }

    float pbv[4], cs[4] = {0.f, 0.f, 0.f, 0.f};
#pragma unroll
    for (int nt = 0; nt < 4; nt++) {
        const int e = (w * 4 + nt) * 16 + cc;
        pbv[nt] = projlb[e] + projb[e];
    }
#pragma unroll
    for (int mt = 0; mt < 4; mt++)
#pragma unroll
        for (int r = 0; r < 4; r++) {
            const float mk = maskv[mt * 16 + quad * 4 + r];
#pragma unroll
            for (int nt = 0; nt < 4; nt++) {
                float v = acc[mt][nt][r] + pbv[nt];
                v = v > 0.f ? v : 0.01f * v;     // leaky_relu(0.01)
                cs[nt] += mk * v;
            }
        }
#pragma unroll
    for (int nt = 0; nt < 4; nt++) {
        cs[nt] += __shfl_xor(cs[nt], 16);
        cs[nt] += __shfl_xor(cs[nt], 32);
    }
    if (quad == 0) {
#pragma unroll
        for (int nt = 0; nt < 4; nt++) sagg[(w * 4 + nt) * 16 + cc] = cs[nt];
    }
    __syncthreads();

    const float agg = sagg[t] / (cnt + 1e-9f);
    sred[t] = selfv * gatew[t] + agg * gatew[256 + t];
    __syncthreads();
    for (int off = 128; off > 0; off >>= 1) {
        if (t < off) sred[t] += sred[t + off];
        __syncthreads();
    }
    if (t == 0) sgate = sigm(sred[0] + gatelb[0] + gateb[0]);
    __syncthreads();

    outX[(size_t)(row_off + b) * 512 + col_off + t] = f2bf(tanhf(selfv + sgate * agg));
}

// ---------- generic bf16 MFMA GEMM: C = act(A @ B^T + bias_f32 + resid_bf16) ----------
__global__ __launch_bounds__(256)
void gemm_bf16(const u16* __restrict__ A, int lda, const u16* __restrict__ B, int ldb,
               u16* __restrict__ C, int ldc, int M, int N, int K,
               const float* __restrict__ bias, const u16* __restrict__ resid, int ldr, int act)
{
    __shared__ u16 As[128][40];
    __shared__ u16 Bs[128][40];

    const int t = threadIdx.x;
    const int m0 = blockIdx.y * 128, n0 = blockIdx.x * 128;
    const int w = t >> 6, lane = t & 63, quad = lane >> 4, cc = lane & 15;
    const int wm = w >> 1, wn = w & 1;

    f32x4 acc[4][4];
#pragma unroll
    for (int mt = 0; mt < 4; mt++)
#pragma unroll
        for (int nt = 0; nt < 4; nt++) acc[mt][nt] = (f32x4){0.f, 0.f, 0.f, 0.f};

    for (int k0 = 0; k0 < K; k0 += 32) {
#pragma unroll
        for (int i = 0; i < 2; i++) {
            const int idx = t + i * 256;
            const int row = idx >> 2, seg = idx & 3;
            const int gm = m0 + row, gn = n0 + row;
            uint4 va = make_uint4(0, 0, 0, 0), vb = make_uint4(0, 0, 0, 0);
            if (gm < M) va = *(const uint4*)(A + (size_t)gm * lda + k0 + seg * 8);
            if (gn < N) vb = *(const uint4*)(B + (size_t)gn * ldb + k0 + seg * 8);
            *(uint4*)&As[row][seg * 8] = va;
            *(uint4*)&Bs[row][seg * 8] = vb;
        }
        __syncthreads();

        bf16x8 af[4], bfr[4];
#pragma unroll
        for (int mt = 0; mt < 4; mt++)
            af[mt] = *(const bf16x8*)&As[wm * 64 + mt * 16 + cc][quad * 8];
#pragma unroll
        for (int nt = 0; nt < 4; nt++)
            bfr[nt] = *(const bf16x8*)&Bs[wn * 64 + nt * 16 + cc][quad * 8];
#pragma unroll
        for (int mt = 0; mt < 4; mt++)
#pragma unroll
            for (int nt = 0; nt < 4; nt++)
                acc[mt][nt] = __builtin_amdgcn_mfma_f32_16x16x32_bf16(af[mt], bfr[nt], acc[mt][nt], 0, 0, 0);
        __syncthreads();
    }

#pragma unroll
    for (int mt = 0; mt < 4; mt++)
#pragma unroll
        for (int r = 0; r < 4; r++) {
            const int gm = m0 + wm * 64 + mt * 16 + quad * 4 + r;
            if (gm >= M) continue;
#pragma unroll
            for (int nt = 0; nt < 4; nt++) {
                const int gn = n0 + wn * 64 + nt * 16 + cc;
                if (gn >= N) continue;
                float x = acc[mt][nt][r];
                if (bias)  x += bias[gn];
                if (resid) x += bf2f(resid[(size_t)gm * ldr + gn]);
                if (act == 1) x = x > 0.f ? x : 0.f;
                C[(size_t)gm * ldc + gn] = f2bf(x);
            }
        }
}

// ---------- LSTM step, gate-to-nt permutation: lane owns all 4 gates of its units ----------
// Wp row n: nb=n>>7, wn=(n>>6)&1, nt=(n>>4)&3, cc=n&15 -> gate=nt, unit j=nb*32+wn*16+cc.
// a1mode: 0=none, 1=store A1 (raw ENC@Wih acc), 2=load A1 and add.
__global__ __launch_bounds__(256)
void lstm_mfma(const u16* __restrict__ ENCb, const u16* __restrict__ hin,
               const u16* __restrict__ Wp, const float* __restrict__ fb,
               float* __restrict__ cst, u16* __restrict__ houtb, float* __restrict__ houtf,
               u16* __restrict__ A1, int step1, int kstart, int kend, int a1mode)
{
    __shared__ u16 As[128][40];
    __shared__ u16 Bs[128][40];

    const int t = threadIdx.x;
    const int m0 = blockIdx.y * 128, n0 = blockIdx.x * 128;
    const int w = t >> 6, lane = t & 63, quad = lane >> 4, cc = lane & 15;
    const int wm = w >> 1, wn = w & 1;

    f32x4 acc[4][4];
#pragma unroll
    for (int mt = 0; mt < 4; mt++)
#pragma unroll
        for (int nt = 0; nt < 4; nt++) acc[mt][nt] = (f32x4){0.f, 0.f, 0.f, 0.f};

    for (int k0 = kstart; k0 < kend; k0 += 32) {
        const u16* Aptr = (k0 < 512) ? ENCb : hin;
        const int kk = (k0 < 512) ? k0 : (k0 - 512);
#pragma unroll
        for (int i = 0; i < 2; i++) {
            const int idx = t + i * 256;
            const int row = idx >> 2, seg = idx & 3;
            uint4 va = *(const uint4*)(Aptr + (size_t)(m0 + row) * 512 + kk + seg * 8);
            uint4 vb = *(const uint4*)(Wp + (size_t)(n0 + row) * 1024 + k0 + seg * 8);
            *(uint4*)&As[row][seg * 8] = va;
            *(uint4*)&Bs[row][seg * 8] = vb;
        }
        __syncthreads();

        bf16x8 af[4], bfr[4];
#pragma unroll
        for (int mt = 0; mt < 4; mt++)
            af[mt] = *(const bf16x8*)&As[wm * 64 + mt * 16 + cc][quad * 8];
#pragma unroll
        for (int nt = 0; nt < 4; nt++)
            bfr[nt] = *(const bf16x8*)&Bs[wn * 64 + nt * 16 + cc][quad * 8];
#pragma unroll
        for (int mt = 0; mt < 4; mt++)
#pragma unroll
            for (int nt = 0; nt < 4; nt++)
                acc[mt][nt] = __builtin_amdgcn_mfma_f32_16x16x32_bf16(af[mt], bfr[nt], acc[mt][nt], 0, 0, 0);
        __syncthreads();
    }

    // epilogue: lane owns gates (i,f,g,o) of unit j for 16 rows; no shfl, no divergence
    const int j = blockIdx.x * 32 + wn * 16 + cc;            // 0..1023
    const float fbi = fb[n0 + wn * 64 +  0 + cc];
    const float fbf = fb[n0 + wn * 64 + 16 + cc];
    const float fbg = fb[n0 + wn * 64 + 32 + cc];
    const float fbo = fb[n0 + wn * 64 + 48 + cc];

#pragma unroll
    for (int mt = 0; mt < 4; mt++)
#pragma unroll
        for (int r = 0; r < 4; r++) {
            const int gm = m0 + wm * 64 + mt * 16 + quad * 4 + r;
            float gi = acc[mt][0][r], gf = acc[mt][1][r];
            float gg = acc[mt][2][r], go = acc[mt][3][r];
            const size_t a1idx = (((size_t)blockIdx.x * 4096 + gm) * 128 + wn * 64 + cc * 4);
            if (a1mode == 1) {
                u16 o[4] = { f2bf(gi), f2bf(gf), f2bf(gg), f2bf(go) };
                *(uint2*)(A1 + a1idx) = *(uint2*)o;
            } else if (a1mode == 2) {
                uint2 v = *(const uint2*)(A1 + a1idx);
                gi += bf2f((u16)(v.x & 0xffff)); gf += bf2f((u16)(v.x >> 16));
                gg += bf2f((u16)(v.y & 0xffff)); go += bf2f((u16)(v.y >> 16));
            }
            gi += fbi; gf += fbf; gg += fbg; go += fbo;
            const float c0 = step1 ? 0.f : cst[(size_t)gm * 1024 + j];
            const float cn = sigm(gf) * c0 + sigm(gi) * tanhf(gg);
            cst[(size_t)gm * 1024 + j] = cn;
            if (j < 512) {
                const float hv = bf2f(ENCb[(size_t)gm * 512 + j]) + sigm(go) * tanhf(cn);
                houtb[(size_t)gm * 512 + j] = f2bf(hv);
                houtf[(size_t)gm * 512 + j] = hv;
            }
        }
}

// ---------- row LayerNorm (bf16 in place, f32 stats; f32 copy of support rows) ----------
__global__ __launch_bounds__(256)
void ln_kernel(u16* __restrict__ X, const float* __restrict__ g, const float* __restrict__ b,
               float* __restrict__ supf)
{
    const int r = blockIdx.x, t = threadIdx.x;
    u16* row = X + (size_t)r * 512;
    const float x0 = bf2f(row[t]), x1 = bf2f(row[t + 256]);

    __shared__ float sr[256];
    sr[t] = x0 + x1; __syncthreads();
    for (int off = 128; off > 0; off >>= 1) { if (t < off) sr[t] += sr[t + off]; __syncthreads(); }
    const float mu = sr[0] / 512.f;
    __syncthreads();
    const float d0 = x0 - mu, d1 = x1 - mu;
    sr[t] = d0 * d0 + d1 * d1; __syncthreads();
    for (int off = 128; off > 0; off >>= 1) { if (t < off) sr[t] += sr[t + off]; __syncthreads(); }
    const float inv = 1.0f / sqrtf(sr[0] / 512.f + 1e-5f);
    const float y0 = g[t] * d0 * inv + b[t];
    const float y1 = g[t + 256] * d1 * inv + b[t + 256];
    row[t]       = f2bf(y0);
    row[t + 256] = f2bf(y1);
    if (r >= 4096) {
        supf[(size_t)(r - 4096) * 512 + t]       = y0;
        supf[(size_t)(r - 4096) * 512 + t + 256] = y1;
    }
}

// ---------- Wp build (gate-to-nt permutation) ----------
__global__ __launch_bounds__(256)
void wp_build(const float* __restrict__ wih, const float* __restrict__ whh,
              const float* __restrict__ bih, const float* __restrict__ bhh,
              u16* __restrict__ Wp, float* __restrict__ fb0p)
{
    const int n = blockIdx.x, t = threadIdx.x;
    const int j = (n >> 7) * 32 + ((n >> 6) & 1) * 16 + (n & 15);
    const int gate = (n >> 4) & 3;
    const int r = gate * 1024 + j;
    const int k = t * 4;
    float4 v;
    if (k < 512) v = *(const float4*)(wih + (size_t)r * 512 + k);
    else         v = *(const float4*)(whh + (size_t)r * 1024 + (k - 512));
    u16 o[4] = { f2bf(v.x), f2bf(v.y), f2bf(v.z), f2bf(v.w) };
    *(uint2*)(Wp + (size_t)n * 1024 + k) = *(uint2*)o;
    if (t == 0) fb0p[n] = bih[r] + bhh[r];
}

// ---------- support_g + fb1p (perm order) ----------
__global__ __launch_bounds__(256)
void sg_cvec(const float* __restrict__ supf, const float* __restrict__ whh,
             const float* __restrict__ fb0p, float* __restrict__ sg, float* __restrict__ fb1p)
{
    __shared__ float ssg[512];
    const int t = threadIdx.x;
#pragma unroll
    for (int rep = 0; rep < 2; rep++) {
        const int jj = t + rep * 256;
        float v = 0.f;
#pragma unroll
        for (int i = 0; i < 5; i++) v += supf[(size_t)i * 512 + jj];
        v *= 0.2f;
        ssg[jj] = v;
        if (blockIdx.x == 0) sg[jj] = v;
    }
    __syncthreads();
    const int n = blockIdx.x * 256 + t;
    const int r = ((n >> 4) & 3) * 1024 + (n >> 7) * 32 + ((n >> 6) & 1) * 16 + (n & 15);
    float a = 0.f;
    for (int jx = 0; jx < 512; jx++)
        a = fmaf(ssg[jx], whh[(size_t)r * 1024 + 512 + jx], a);
    fb1p[n] = fb0p[n] + a;
}

// ---------- final: out[b] = dot(hf[b], sg) -> f32 ----------
__global__ __launch_bounds__(256)
void final_dot(const float* __restrict__ hf, const float* __restrict__ sg,
               float* __restrict__ out)
{
    const int wid = threadIdx.x >> 6, lane = threadIdx.x & 63;
    const int b = blockIdx.x * 4 + wid;
    const float* hr = hf + (size_t)b * 512;
    float s = 0.f;
#pragma unroll
    for (int q = 0; q < 8; q++) s = fmaf(hr[lane + q * 64], sg[lane + q * 64], s);
    for (int off = 32; off > 0; off >>= 1) s += __shfl_down(s, off);
    if (lane == 0) {
        if (!isfinite(s)) s = 7777.0f;   // triage tripwire
        out[b] = s;
    }
}

// ---------- launcher ----------
extern "C" void kernel_launch(void* const* d_in, const int* in_sizes, int n_in,
                              void* d_out, int out_size, void* d_ws, size_t ws_size,
                              hipStream_t stream)
{
    (void)in_sizes; (void)n_in; (void)out_size;
    const int* query     = (const int*)d_in[0];
    const int* support   = (const int*)d_in[1];
    const int* q_l1      = (const int*)d_in[2];
    const int* q_r1      = (const int*)d_in[3];
    const int* s_l1      = (const int*)d_in[4];
    const int* s_r1      = (const int*)d_in[5];
    const float* emb     = (const float*)d_in[6];
    const float* projw   = (const float*)d_in[7];
    const float* projlb  = (const float*)d_in[8];
    const float* projb   = (const float*)d_in[9];
    const float* gatew   = (const float*)d_in[10];
    const float* gatelb  = (const float*)d_in[11];
    const float* gateb   = (const float*)d_in[12];
    const float* sew1    = (const float*)d_in[13];
    const float* seb1    = (const float*)d_in[14];
    const float* sew2    = (const float*)d_in[15];
    const float* seb2    = (const float*)d_in[16];
    const float* lng     = (const float*)d_in[17];
    const float* lnb     = (const float*)d_in[18];
    const float* wih     = (const float*)d_in[19];
    const float* whh     = (const float*)d_in[20];
    const float* bih     = (const float*)d_in[21];
    const float* bhh     = (const float*)d_in[22];

    // ---- workspace layout (float offsets) ----
    float* base   = (float*)d_ws;
    float* sg     = base;                        // 512
    float* fb0p   = base + 512;                  // 4096
    float* fb1p   = base + 4608;                 // 4096
    float* supf   = base + 8704;                 // 5*512
    u16*   projwb = (u16*)(base + 11264);        // 256*256 bf16
    u16*   sew1b  = (u16*)(base + 44032);        // 1024*512 bf16
    u16*   sew2b  = (u16*)(base + 306176);       // 512*1024 bf16
    u16*   Wp     = (u16*)(base + 568320);       // 4096*1024 bf16 (perm)
    u16*   X      = (u16*)(base + 2665472);      // [4104,512]  bf16
    u16*   ENCb   = (u16*)(base + 3716096);      // [4104,512]  bf16
    u16*   hb0    = (u16*)(base + 4766720);      // [4096,512]  bf16
    u16*   hb1    = (u16*)(base + 5815296);      // [4096,512]  bf16
    float* hf     = base + 6863872;              // [4096,512]  f32
    u16*   Hb     = (u16*)(base + 8961024);      // [4104,1024] bf16 (dead after GEMM2)
    float* cst    = base + 8961024;              // [4096,1024] f32 overlays Hb
    u16*   A1     = (u16*)(base + 13155328);     // [32][4096][128] bf16 (optional)

    const size_t NEEDED     = 13155328ull * 4ull;               // 52.6 MB
    const size_t NEEDED_BIG = (13155328ull + 8388608ull) * 4ull; // 86.2 MB
    if (ws_size < NEEDED) {
        signal_fail<<<16, 256, 0, stream>>>((float*)d_out);
        return;
    }
    const bool use_a1 = (ws_size >= NEEDED_BIG);

    // weight conversions (f32 -> bf16 scratch)
    conv_bf16<<<64, 256, 0, stream>>>(projw, projwb, 65536);
    conv_bf16<<<512, 256, 0, stream>>>(sew1, sew1b, 524288);
    conv_bf16<<<512, 256, 0, stream>>>(sew2, sew2b, 524288);
    wp_build<<<4096, 256, 0, stream>>>(wih, whh, bih, bhh, Wp, fb0p);

    // Part A: neighbor encoders -> X (bf16)
    neighbor_mfma<<<4096, 256, 0, stream>>>(q_l1, query, 2, 0, emb, projwb, projlb, projb,
                                            gatew, gatelb, gateb, X, 0, 0);
    neighbor_mfma<<<4096, 256, 0, stream>>>(q_r1, query, 2, 1, emb, projwb, projlb, projb,
                                            gatew, gatelb, gateb, X, 0, 256);
    neighbor_mfma<<<5, 256, 0, stream>>>(s_l1, support, 2, 0, emb, projwb, projlb, projb,
                                         gatew, gatelb, gateb, X, 4096, 0);
    neighbor_mfma<<<5, 256, 0, stream>>>(s_r1, support, 2, 1, emb, projwb, projlb, projb,
                                         gatew, gatelb, gateb, X, 4096, 256);

    // Part B: support encoder (MFMA)
    gemm_bf16<<<dim3(8, 33), 256, 0, stream>>>(
        X, 512, sew1b, 512, Hb, 1024, 4101, 1024, 512, seb1, nullptr, 0, 1);
    gemm_bf16<<<dim3(4, 33), 256, 0, stream>>>(
        Hb, 1024, sew2b, 1024, ENCb, 512, 4101, 512, 1024, seb2, X, 512, 0);
    ln_kernel<<<4101, 256, 0, stream>>>(ENCb, lng, lnb, supf);

    sg_cvec<<<16, 256, 0, stream>>>(supf, whh, fb0p, sg, fb1p);

    // LSTM (gate-to-nt epilogue; A1 caching when workspace allows)
    if (use_a1) {
        lstm_mfma<<<dim3(32, 32), 256, 0, stream>>>(ENCb, hb0, Wp, fb0p, cst, hb0, hf, A1, 1, 0, 512, 1);
        lstm_mfma<<<dim3(32, 32), 256, 0, stream>>>(ENCb, hb0, Wp, fb1p, cst, hb1, hf, A1, 0, 512, 1024, 2);
        lstm_mfma<<<dim3(32, 32), 256, 0, stream>>>(ENCb, hb1, Wp, fb1p, cst, hb0, hf, A1, 0, 512, 1024, 2);
        lstm_mfma<<<dim3(32, 32), 256, 0, stream>>>(ENCb, hb0, Wp, fb1p, cst, hb1, hf, A1, 0, 512, 1024, 2);
    } else {
        lstm_mfma<<<dim3(32, 32), 256, 0, stream>>>(ENCb, hb0, Wp, fb0p, cst, hb0, hf, nullptr, 1, 0, 512, 0);
        lstm_mfma<<<dim3(32, 32), 256, 0, stream>>>(ENCb, hb0, Wp, fb1p, cst, hb1, hf, nullptr, 0, 0, 1024, 0);
        lstm_mfma<<<dim3(32, 32), 256, 0, stream>>>(ENCb, hb1, Wp, fb1p, cst, hb0, hf, nullptr, 0, 0, 1024, 0);
        lstm_mfma<<<dim3(32, 32), 256, 0, stream>>>(ENCb, hb0, Wp, fb1p, cst, hb1, hf, nullptr, 0, 0, 1024, 0);
    }

    // final scores (f32 out)
    final_dot<<<1024, 256, 0, stream>>>(hf, sg, (float*)d_out);
}